// Round 1
// baseline (405.526 us; speedup 1.0000x reference)
//
#include <hip/hip_runtime.h>
#include <hip/hip_bf16.h>
#include <stdint.h>

// ---------------- helpers ----------------
__device__ __forceinline__ float bf2f(unsigned short u) {
    unsigned int x = ((unsigned int)u) << 16;
    return __uint_as_float(x);
}
__device__ __forceinline__ unsigned short f2bf(float f) {
    unsigned int x = __float_as_uint(f);
    unsigned int lsb = (x >> 16) & 1u;
    x += 0x7fffu + lsb;           // round-to-nearest-even
    return (unsigned short)(x >> 16);
}
// dtype-flexible float load: isbf ? bf16 : f32
__device__ __forceinline__ float loadF(const void* p, int i, int isbf) {
    return isbf ? bf2f(((const unsigned short*)p)[i]) : ((const float*)p)[i];
}

// ---------------- dtype detection ----------------
// flags[0] = floats are bf16 (1) or f32 (0)
// flags[1] = edge_index is int64 (1) or int32 (0)
__global__ void k_detect(const void* x, const void* eidx, int* flags) {
    if (threadIdx.x == 0 && blockIdx.x == 0) {
        const unsigned short* u = (const unsigned short*)x;
        int bf = 1;
        for (int k = 0; k < 64; ++k) {
            float v = bf2f(u[2 * k]);     // bf16: element 2k (sane); f32: mantissa junk
            float a = fabsf(v);
            if (!(a == 0.0f || (a > 1e-30f && a < 1e4f))) { bf = 0; break; }
        }
        flags[0] = bf;
        const int* ip = (const int*)eidx;
        int i64 = 1;
        for (int k = 0; k < 64; ++k) {
            if (ip[2 * k + 1] != 0) { i64 = 0; break; }   // high words zero iff int64
        }
        flags[1] = i64;
    }
}

// ---------------- degree histogram (dst row) ----------------
__global__ void k_deg(const void* eidx, int E, int* deg, const int* flags) {
    int i64 = flags[1];
    int i = blockIdx.x * blockDim.x + threadIdx.x;
    int stride = gridDim.x * blockDim.x;
    for (; i < E; i += stride) {
        int d = i64 ? (int)((const long long*)eidx)[E + i] : ((const int*)eidx)[E + i];
        atomicAdd(&deg[d], 1);
    }
}

__global__ void k_dinv(const int* deg, float* dinv, int n) {
    int i = blockIdx.x * blockDim.x + threadIdx.x;
    if (i < n) dinv[i] = rsqrtf((float)(deg[i] + 1));   // +1 = self loop
}

// ---------------- exclusive scan of deg -> rowptr (3 kernels) ----------------
__global__ void k_bsum(const int* deg, int n, int* bsum) {
    __shared__ int s[256];
    int b = blockIdx.x, t = threadIdx.x;
    int base = b * 1024;
    int v = 0;
    for (int k = t; k < 1024; k += 256) {
        int i = base + k;
        v += (i < n) ? deg[i] : 0;
    }
    s[t] = v; __syncthreads();
    for (int off = 128; off > 0; off >>= 1) {
        if (t < off) s[t] += s[t + off];
        __syncthreads();
    }
    if (t == 0) bsum[b] = s[0];
}
__global__ void k_scan_bsums(const int* bsum, int nb, int* boff, int* rowptr, int n) {
    if (threadIdx.x == 0 && blockIdx.x == 0) {
        int acc = 0;
        for (int b = 0; b < nb; ++b) { boff[b] = acc; acc += bsum[b]; }
        rowptr[n] = acc;   // == E
    }
}
__global__ void k_scan_write(const int* deg, int n, const int* boff, int* rowptr) {
    __shared__ int s[1024];
    int b = blockIdx.x, t = threadIdx.x;
    int i = b * 1024 + t;
    int v = (i < n) ? deg[i] : 0;
    s[t] = v; __syncthreads();
    for (int off = 1; off < 1024; off <<= 1) {
        int add = (t >= off) ? s[t - off] : 0;
        __syncthreads();
        s[t] += add;
        __syncthreads();
    }
    if (i < n) rowptr[i] = boff[b] + s[t] - v;   // exclusive scan
}

__global__ void k_copy(const int* a, int* b, int n) {
    int i = blockIdx.x * blockDim.x + threadIdx.x;
    if (i < n) b[i] = a[i];
}

// ---------------- CSR fill ----------------
__global__ void k_fill(const void* eidx, int E, const float* dinv, int* cursor,
                       int* col, float* wsrc, const int* flags) {
    int i64 = flags[1];
    int i = blockIdx.x * blockDim.x + threadIdx.x;
    int stride = gridDim.x * blockDim.x;
    for (; i < E; i += stride) {
        int s, d;
        if (i64) {
            s = (int)((const long long*)eidx)[i];
            d = (int)((const long long*)eidx)[E + i];
        } else {
            s = ((const int*)eidx)[i];
            d = ((const int*)eidx)[E + i];
        }
        int pos = atomicAdd(&cursor[d], 1);
        col[pos] = s;
        wsrc[pos] = dinv[s];
    }
}

// ---------------- tiny matrices: M = W1^3 W2 ; cvecs = {g3,g2,g1,b2} ----------------
__global__ void k_consts(const void* W1, const void* b1, const void* W2, const void* b2,
                         float* M, float* cvecs, const int* flags) {
    __shared__ float A[64 * 64], T1[64 * 64], T2[64 * 64], B2[64 * 16];
    __shared__ float bv[64], bw1[64], bw2[64];
    int bf = flags[0];
    int t = threadIdx.x;   // 256 threads
    for (int i = t; i < 4096; i += 256) A[i] = loadF(W1, i, bf);
    for (int i = t; i < 1024; i += 256) B2[i] = loadF(W2, i, bf);
    if (t < 64) bv[t] = loadF(b1, t, bf);
    __syncthreads();
    // T1 = A @ A
    for (int idx = t; idx < 4096; idx += 256) {
        int i = idx >> 6, j = idx & 63;
        float acc = 0.f;
        for (int k = 0; k < 64; ++k) acc += A[i * 64 + k] * A[k * 64 + j];
        T1[idx] = acc;
    }
    __syncthreads();
    // T2 = T1 @ A
    for (int idx = t; idx < 4096; idx += 256) {
        int i = idx >> 6, j = idx & 63;
        float acc = 0.f;
        for (int k = 0; k < 64; ++k) acc += T1[i * 64 + k] * A[k * 64 + j];
        T2[idx] = acc;
    }
    // bw1 = b1^T W1 ; bw2 = bw1 W1
    if (t < 64) {
        float acc = 0.f;
        for (int i = 0; i < 64; ++i) acc += bv[i] * A[i * 64 + t];
        bw1[t] = acc;
    }
    __syncthreads();
    if (t < 64) {
        float acc = 0.f;
        for (int i = 0; i < 64; ++i) acc += bw1[i] * A[i * 64 + t];
        bw2[t] = acc;
    }
    __syncthreads();
    // M = T2 @ B2  (64x16)
    for (int idx = t; idx < 1024; idx += 256) {
        int i = idx >> 4, j = idx & 15;
        float acc = 0.f;
        for (int k = 0; k < 64; ++k) acc += T2[i * 64 + k] * B2[k * 16 + j];
        M[idx] = acc;
    }
    // cvecs: [0:16)=g3=b1W1^2W2, [16:32)=g2=b1W1W2, [32:48)=g1=b1W2, [48:64)=b2
    if (t < 16) {
        float a3 = 0.f, a2 = 0.f, a1 = 0.f;
        for (int i = 0; i < 64; ++i) {
            float w = B2[i * 16 + t];
            a3 += bw2[i] * w;
            a2 += bw1[i] * w;
            a1 += bv[i] * w;
        }
        cvecs[t] = a3;
        cvecs[16 + t] = a2;
        cvecs[32 + t] = a1;
        cvecs[48 + t] = loadF(b2, t, bf);
    }
}

// ---------------- y0 = x @ M  (N x 64 @ 64 x 16) ----------------
__global__ void k_xm(const void* x, const float* M, float* y0, int n, const int* flags) {
    __shared__ float Ms[64 * 16];
    __shared__ float xs[16 * 64];
    int bf = flags[0];
    int t = threadIdx.x;   // 256
    for (int i = t; i < 1024; i += 256) Ms[i] = M[i];
    int base = blockIdx.x * 16;
    for (int k = t; k < 1024; k += 256) {
        int r = k >> 6, cc = k & 63;
        int row = base + r;
        xs[k] = (row < n) ? loadF(x, row * 64 + cc, bf) : 0.f;
    }
    __syncthreads();
    int r = t >> 4, c = t & 15;
    int row = base + r;
    if (row < n) {
        float acc = 0.f;
#pragma unroll
        for (int k = 0; k < 64; ++k) acc += xs[r * 64 + k] * Ms[k * 16 + c];
        y0[row * 16 + c] = acc;
    }
}

// ---------------- propagation: yout = dinv*(sum wsrc*yin[col]) + dinv^2*yin + cvec ----------------
__global__ void k_prop(const float* yin, void* yout, const int* rowptr, const int* col,
                       const float* wsrc, const float* dinv, const float* cvec,
                       int n, int is_final, const int* flags) {
    int tid = blockIdx.x * blockDim.x + threadIdx.x;
    int v = tid >> 4, c = tid & 15;
    if (v >= n) return;
    int beg = rowptr[v], end = rowptr[v + 1];
    float acc = 0.f;
    for (int j = beg; j < end; ++j)
        acc += wsrc[j] * yin[col[j] * 16 + c];
    float dv = dinv[v];
    float val = dv * acc + dv * dv * yin[v * 16 + c] + cvec[c];
    int o = v * 16 + c;
    if (is_final && flags[0]) ((unsigned short*)yout)[o] = f2bf(val);
    else                      ((float*)yout)[o] = val;
}

// ---------------- launch ----------------
extern "C" void kernel_launch(void* const* d_in, const int* in_sizes, int n_in,
                              void* d_out, int out_size, void* d_ws, size_t ws_size,
                              hipStream_t stream) {
    const void* x  = d_in[0];
    const void* W1 = d_in[1];
    const void* b1 = d_in[2];
    const void* W2 = d_in[3];
    const void* b2 = d_in[4];
    const void* ei = d_in[5];

    const int n = in_sizes[0] / 64;       // 100000
    const int E = in_sizes[5] / 2;        // 1000000
    const int nb = (n + 1023) / 1024;

    // workspace carve (256B aligned); total ~23 MB
    char* base = (char*)d_ws;
    size_t off = 0;
    auto carve = [&](size_t bytes) -> void* {
        void* r = base + off;
        off = (off + bytes + 255) & ~(size_t)255;
        return r;
    };
    int*   flags  = (int*)carve(8);
    int*   deg    = (int*)carve((size_t)n * 4);
    float* dinv   = (float*)carve((size_t)n * 4);
    int*   rowptr = (int*)carve((size_t)(n + 1) * 4);
    int*   cursor = (int*)carve((size_t)n * 4);
    int*   bsum   = (int*)carve((size_t)nb * 4);
    int*   boff   = (int*)carve((size_t)nb * 4);
    int*   col    = (int*)carve((size_t)E * 4);
    float* wsrc   = (float*)carve((size_t)E * 4);
    float* Mm     = (float*)carve(1024 * 4);
    float* cvecs  = (float*)carve(64 * 4);
    float* y0     = (float*)carve((size_t)n * 16 * 4);
    float* y1     = (float*)carve((size_t)n * 16 * 4);
    (void)ws_size; (void)n_in; (void)out_size;

    hipMemsetAsync(deg, 0, (size_t)n * 4, stream);
    k_detect<<<1, 64, 0, stream>>>(x, ei, flags);
    k_deg<<<2048, 256, 0, stream>>>(ei, E, deg, flags);
    k_dinv<<<(n + 255) / 256, 256, 0, stream>>>(deg, dinv, n);
    k_bsum<<<nb, 256, 0, stream>>>(deg, n, bsum);
    k_scan_bsums<<<1, 64, 0, stream>>>(bsum, nb, boff, rowptr, n);
    k_scan_write<<<nb, 1024, 0, stream>>>(deg, n, boff, rowptr);
    k_copy<<<(n + 255) / 256, 256, 0, stream>>>(rowptr, cursor, n);
    k_fill<<<2048, 256, 0, stream>>>(ei, E, dinv, cursor, col, wsrc, flags);
    k_consts<<<1, 256, 0, stream>>>(W1, b1, W2, b2, Mm, cvecs, flags);
    k_xm<<<(n + 15) / 16, 256, 0, stream>>>(x, Mm, y0, n, flags);

    const int pgrid = (n * 16 + 255) / 256;
    // y1 = A y0 + g3 ; y0 = A y1 + g2 ; y1 = A y0 + g1 ; out = A y1 + b2
    k_prop<<<pgrid, 256, 0, stream>>>(y0, y1, rowptr, col, wsrc, dinv, cvecs + 0,  n, 0, flags);
    k_prop<<<pgrid, 256, 0, stream>>>(y1, y0, rowptr, col, wsrc, dinv, cvecs + 16, n, 0, flags);
    k_prop<<<pgrid, 256, 0, stream>>>(y0, y1, rowptr, col, wsrc, dinv, cvecs + 32, n, 0, flags);
    k_prop<<<pgrid, 256, 0, stream>>>(y1, d_out, rowptr, col, wsrc, dinv, cvecs + 48, n, 1, flags);
}

// Round 2
// 242.024 us; speedup vs baseline: 1.6756x; 1.6756x over previous
//
#include <hip/hip_runtime.h>
#include <hip/hip_bf16.h>
#include <stdint.h>

// ---------------- helpers ----------------
__device__ __forceinline__ float bf2f(unsigned short u) {
    unsigned int x = ((unsigned int)u) << 16;
    return __uint_as_float(x);
}
__device__ __forceinline__ unsigned short f2bf(float f) {
    unsigned int x = __float_as_uint(f);
    unsigned int lsb = (x >> 16) & 1u;
    x += 0x7fffu + lsb;           // round-to-nearest-even
    return (unsigned short)(x >> 16);
}
__device__ __forceinline__ float loadF(const void* p, int i, int isbf) {
    return isbf ? bf2f(((const unsigned short*)p)[i]) : ((const float*)p)[i];
}

// ---------------- dtype detection (64-lane parallel) ----------------
// flags[0] = floats are bf16 (1) or f32 (0)
// flags[1] = edge_index is int64 (1) or int32 (0)
__global__ void k_detect(const void* x, const void* eidx, int* flags) {
    int l = threadIdx.x;   // 64 threads
    const unsigned short* u = (const unsigned short*)x;
    float a = fabsf(bf2f(u[2 * l]));
    bool ok = (a == 0.0f) || (a > 1e-30f && a < 1e4f);
    unsigned long long mbf = __ballot(ok);
    const int* ip = (const int*)eidx;
    unsigned long long mi64 = __ballot(ip[2 * l + 1] == 0);
    if (l == 0) {
        flags[0] = (mbf  == ~0ULL) ? 1 : 0;
        flags[1] = (mi64 == ~0ULL) ? 1 : 0;
    }
}

// ---------------- degree histogram (dst row) ----------------
__global__ void k_deg(const void* eidx, int E, int* deg, const int* flags) {
    int i64 = flags[1];
    int i = blockIdx.x * blockDim.x + threadIdx.x;
    int stride = gridDim.x * blockDim.x;
    for (; i < E; i += stride) {
        int d = i64 ? (int)((const long long*)eidx)[E + i] : ((const int*)eidx)[E + i];
        atomicAdd(&deg[d], 1);
    }
}

// ---------------- exclusive scan of deg -> rowptr ----------------
__global__ void k_bsum(const int* deg, int n, int* bsum) {
    __shared__ int s[256];
    int b = blockIdx.x, t = threadIdx.x;
    int base = b * 1024;
    int v = 0;
    for (int k = t; k < 1024; k += 256) {
        int i = base + k;
        v += (i < n) ? deg[i] : 0;
    }
    s[t] = v; __syncthreads();
    for (int off = 128; off > 0; off >>= 1) {
        if (t < off) s[t] += s[t + off];
        __syncthreads();
    }
    if (t == 0) bsum[b] = s[0];
}
__global__ void k_scan_bsums(const int* bsum, int nb, int* boff, int* rowptr, int n) {
    if (threadIdx.x == 0 && blockIdx.x == 0) {
        int acc = 0;
        for (int b = 0; b < nb; ++b) { boff[b] = acc; acc += bsum[b]; }
        rowptr[n] = acc;   // == E
    }
}
// fused: rowptr + cursor + dinv
__global__ void k_scan_write(const int* deg, int n, const int* boff, int* rowptr,
                             int* cursor, float* dinv) {
    __shared__ int s[1024];
    int b = blockIdx.x, t = threadIdx.x;
    int i = b * 1024 + t;
    int v = (i < n) ? deg[i] : 0;
    s[t] = v; __syncthreads();
    for (int off = 1; off < 1024; off <<= 1) {
        int add = (t >= off) ? s[t - off] : 0;
        __syncthreads();
        s[t] += add;
        __syncthreads();
    }
    if (i < n) {
        int r = boff[b] + s[t] - v;   // exclusive scan
        rowptr[i] = r;
        cursor[i] = r;
        dinv[i] = rsqrtf((float)(v + 1));   // +1 self loop
    }
}

// ---------------- CSR fill ----------------
__global__ void k_fill(const void* eidx, int E, const float* dinv, int* cursor,
                       int* col, float* wsrc, const int* flags) {
    int i64 = flags[1];
    int i = blockIdx.x * blockDim.x + threadIdx.x;
    int stride = gridDim.x * blockDim.x;
    for (; i < E; i += stride) {
        int s, d;
        if (i64) {
            s = (int)((const long long*)eidx)[i];
            d = (int)((const long long*)eidx)[E + i];
        } else {
            s = ((const int*)eidx)[i];
            d = ((const int*)eidx)[E + i];
        }
        int pos = atomicAdd(&cursor[d], 1);
        col[pos] = s;
        wsrc[pos] = dinv[s];
    }
}

// ---------------- consts: M = W1^3 W2 ; cvecs = {g3,g2,g1,b2} ----------------
// 256 threads, 4x4 register blocking, padded intermediates (stride 68).
#define TS 68
__global__ void k_consts(const void* W1, const void* b1, const void* W2, const void* b2,
                         float* M, float* cvecs, const int* flags) {
    __shared__ float A[64 * 64];       // row-major, stride 64
    __shared__ float T1[64 * TS];      // stride 68 (pad: bank-spread + 16B align)
    __shared__ float T2[64 * TS];
    __shared__ float B2[64 * 16];
    __shared__ float bv[64], bw1[64], bw2[64];
    int bf = flags[0];
    int t = threadIdx.x;   // 256 threads
    for (int i = t; i < 4096; i += 256) A[i] = loadF(W1, i, bf);
    for (int i = t; i < 1024; i += 256) B2[i] = loadF(W2, i, bf);
    if (t < 64) bv[t] = loadF(b1, t, bf);
    __syncthreads();

    const int i0 = (t >> 4) * 4;   // 0..60
    const int j0 = (t & 15) * 4;   // 0..60
    // ---- T1 = A @ A ----
    {
        float acc[4][4] = {};
#pragma unroll 8
        for (int k = 0; k < 64; ++k) {
            float a0 = A[(i0 + 0) * 64 + k];
            float a1 = A[(i0 + 1) * 64 + k];
            float a2 = A[(i0 + 2) * 64 + k];
            float a3 = A[(i0 + 3) * 64 + k];
            float4 bq = *(const float4*)&A[k * 64 + j0];
            acc[0][0] += a0 * bq.x; acc[0][1] += a0 * bq.y; acc[0][2] += a0 * bq.z; acc[0][3] += a0 * bq.w;
            acc[1][0] += a1 * bq.x; acc[1][1] += a1 * bq.y; acc[1][2] += a1 * bq.z; acc[1][3] += a1 * bq.w;
            acc[2][0] += a2 * bq.x; acc[2][1] += a2 * bq.y; acc[2][2] += a2 * bq.z; acc[2][3] += a2 * bq.w;
            acc[3][0] += a3 * bq.x; acc[3][1] += a3 * bq.y; acc[3][2] += a3 * bq.z; acc[3][3] += a3 * bq.w;
        }
#pragma unroll
        for (int ii = 0; ii < 4; ++ii)
            *(float4*)&T1[(i0 + ii) * TS + j0] = make_float4(acc[ii][0], acc[ii][1], acc[ii][2], acc[ii][3]);
    }
    // bw1 = b1^T W1 (uses A, bv only)
    if (t < 64) {
        float acc = 0.f;
#pragma unroll 8
        for (int i = 0; i < 64; ++i) acc += bv[i] * A[i * 64 + t];
        bw1[t] = acc;
    }
    __syncthreads();

    // ---- T2 = T1 @ A ----
    {
        float acc[4][4] = {};
#pragma unroll 8
        for (int k = 0; k < 64; ++k) {
            float a0 = T1[(i0 + 0) * TS + k];
            float a1 = T1[(i0 + 1) * TS + k];
            float a2 = T1[(i0 + 2) * TS + k];
            float a3 = T1[(i0 + 3) * TS + k];
            float4 bq = *(const float4*)&A[k * 64 + j0];
            acc[0][0] += a0 * bq.x; acc[0][1] += a0 * bq.y; acc[0][2] += a0 * bq.z; acc[0][3] += a0 * bq.w;
            acc[1][0] += a1 * bq.x; acc[1][1] += a1 * bq.y; acc[1][2] += a1 * bq.z; acc[1][3] += a1 * bq.w;
            acc[2][0] += a2 * bq.x; acc[2][1] += a2 * bq.y; acc[2][2] += a2 * bq.z; acc[2][3] += a2 * bq.w;
            acc[3][0] += a3 * bq.x; acc[3][1] += a3 * bq.y; acc[3][2] += a3 * bq.z; acc[3][3] += a3 * bq.w;
        }
#pragma unroll
        for (int ii = 0; ii < 4; ++ii)
            *(float4*)&T2[(i0 + ii) * TS + j0] = make_float4(acc[ii][0], acc[ii][1], acc[ii][2], acc[ii][3]);
    }
    // bw2 = bw1 W1
    if (t < 64) {
        float acc = 0.f;
#pragma unroll 8
        for (int i = 0; i < 64; ++i) acc += bw1[i] * A[i * 64 + t];
        bw2[t] = acc;
    }
    __syncthreads();

    // ---- M = T2 @ B2 (64x16): thread -> (i = t>>2, j0m = (t&3)*4) ----
    {
        int i = t >> 2, j0m = (t & 3) * 4;
        float4 acc = {0.f, 0.f, 0.f, 0.f};
#pragma unroll 8
        for (int k = 0; k < 64; ++k) {
            float a = T2[i * TS + k];
            float4 bq = *(const float4*)&B2[k * 16 + j0m];
            acc.x += a * bq.x; acc.y += a * bq.y; acc.z += a * bq.z; acc.w += a * bq.w;
        }
        *(float4*)&M[i * 16 + j0m] = acc;
    }
    // cvecs: [0:16)=g3=b1W1^2W2, [16:32)=g2=b1W1W2, [32:48)=g1=b1W2, [48:64)=b2
    if (t < 16) {
        float a3 = 0.f, a2 = 0.f, a1 = 0.f;
#pragma unroll 8
        for (int i = 0; i < 64; ++i) {
            float w = B2[i * 16 + t];
            a3 += bw2[i] * w;
            a2 += bw1[i] * w;
            a1 += bv[i] * w;
        }
        cvecs[t] = a3;
        cvecs[16 + t] = a2;
        cvecs[32 + t] = a1;
        cvecs[48 + t] = loadF(b2, t, bf);
    }
}

// ---------------- y0 = x @ M  (N x 64 @ 64 x 16) ----------------
__global__ void k_xm(const void* x, const float* M, float* y0, int n, const int* flags) {
    __shared__ float Ms[64 * 16];
    __shared__ float xs[16 * 64];
    int bf = flags[0];
    int t = threadIdx.x;   // 256
    if (t < 256) ((float4*)Ms)[t] = ((const float4*)M)[t];
    int base = blockIdx.x * 16;
    if (!bf) {
        // one float4 per thread: 256 * 4 = 1024 floats = 16 rows
        int row = base + (t >> 4);
        float4 v = make_float4(0.f, 0.f, 0.f, 0.f);
        if (row < n) v = ((const float4*)x)[base * 16 + t];
        ((float4*)xs)[t] = v;
    } else {
        for (int k = t; k < 1024; k += 256) {
            int r = k >> 6, cc = k & 63;
            int row = base + r;
            xs[k] = (row < n) ? bf2f(((const unsigned short*)x)[row * 64 + cc]) : 0.f;
        }
    }
    __syncthreads();
    int r = t >> 4, c = t & 15;
    int row = base + r;
    if (row < n) {
        float acc = 0.f;
#pragma unroll
        for (int k = 0; k < 64; ++k) acc += xs[r * 64 + k] * Ms[k * 16 + c];
        y0[row * 16 + c] = acc;
    }
}

// ---------------- propagation (float4 per lane, 4 lanes per node) ----------------
// yout = dinv*(sum wsrc*yin[col]) + dinv^2*yin + cvec
__global__ void k_prop(const float* yin, void* yout, const int* rowptr, const int* col,
                       const float* wsrc, const float* dinv, const float* cvec,
                       int n, int is_final, const int* flags) {
    int tid = blockIdx.x * blockDim.x + threadIdx.x;
    int v = tid >> 2, q = tid & 3;
    if (v >= n) return;
    int beg = rowptr[v], end = rowptr[v + 1];
    float4 acc = {0.f, 0.f, 0.f, 0.f};
    for (int j = beg; j < end; ++j) {
        int ci = col[j];
        float w = wsrc[j];
        float4 yv = *(const float4*)&yin[ci * 16 + q * 4];
        acc.x += w * yv.x; acc.y += w * yv.y; acc.z += w * yv.z; acc.w += w * yv.w;
    }
    float dv = dinv[v];
    float d2 = dv * dv;
    float4 self = *(const float4*)&yin[v * 16 + q * 4];
    float4 cv = *(const float4*)&cvec[q * 4];
    float4 val;
    val.x = dv * acc.x + d2 * self.x + cv.x;
    val.y = dv * acc.y + d2 * self.y + cv.y;
    val.z = dv * acc.z + d2 * self.z + cv.z;
    val.w = dv * acc.w + d2 * self.w + cv.w;
    int o = v * 16 + q * 4;
    if (is_final && flags[0]) {
        ushort4 ov;
        ov.x = f2bf(val.x); ov.y = f2bf(val.y); ov.z = f2bf(val.z); ov.w = f2bf(val.w);
        *(ushort4*)&((unsigned short*)yout)[o] = ov;
    } else {
        *(float4*)&((float*)yout)[o] = val;
    }
}

// ---------------- launch ----------------
extern "C" void kernel_launch(void* const* d_in, const int* in_sizes, int n_in,
                              void* d_out, int out_size, void* d_ws, size_t ws_size,
                              hipStream_t stream) {
    const void* x  = d_in[0];
    const void* W1 = d_in[1];
    const void* b1 = d_in[2];
    const void* W2 = d_in[3];
    const void* b2 = d_in[4];
    const void* ei = d_in[5];

    const int n = in_sizes[0] / 64;       // 100000
    const int E = in_sizes[5] / 2;        // 1000000
    const int nb = (n + 1023) / 1024;

    char* base = (char*)d_ws;
    size_t off = 0;
    auto carve = [&](size_t bytes) -> void* {
        void* r = base + off;
        off = (off + bytes + 255) & ~(size_t)255;
        return r;
    };
    int*   flags  = (int*)carve(8);
    int*   deg    = (int*)carve((size_t)n * 4);
    float* dinv   = (float*)carve((size_t)n * 4);
    int*   rowptr = (int*)carve((size_t)(n + 1) * 4);
    int*   cursor = (int*)carve((size_t)n * 4);
    int*   bsum   = (int*)carve((size_t)nb * 4);
    int*   boff   = (int*)carve((size_t)nb * 4);
    int*   col    = (int*)carve((size_t)E * 4);
    float* wsrc   = (float*)carve((size_t)E * 4);
    float* Mm     = (float*)carve(1024 * 4);
    float* cvecs  = (float*)carve(64 * 4);
    float* y0     = (float*)carve((size_t)n * 16 * 4);
    float* y1     = (float*)carve((size_t)n * 16 * 4);
    (void)ws_size; (void)n_in; (void)out_size;

    hipMemsetAsync(deg, 0, (size_t)n * 4, stream);
    k_detect<<<1, 64, 0, stream>>>(x, ei, flags);
    k_deg<<<2048, 256, 0, stream>>>(ei, E, deg, flags);
    k_bsum<<<nb, 256, 0, stream>>>(deg, n, bsum);
    k_scan_bsums<<<1, 64, 0, stream>>>(bsum, nb, boff, rowptr, n);
    k_scan_write<<<nb, 1024, 0, stream>>>(deg, n, boff, rowptr, cursor, dinv);
    k_fill<<<2048, 256, 0, stream>>>(ei, E, dinv, cursor, col, wsrc, flags);
    k_consts<<<1, 256, 0, stream>>>(W1, b1, W2, b2, Mm, cvecs, flags);
    k_xm<<<(n + 15) / 16, 256, 0, stream>>>(x, Mm, y0, n, flags);

    const int pgrid = (n * 4 + 255) / 256;
    // y1 = A y0 + g3 ; y0 = A y1 + g2 ; y1 = A y0 + g1 ; out = A y1 + b2
    k_prop<<<pgrid, 256, 0, stream>>>(y0, y1, rowptr, col, wsrc, dinv, cvecs + 0,  n, 0, flags);
    k_prop<<<pgrid, 256, 0, stream>>>(y1, y0, rowptr, col, wsrc, dinv, cvecs + 16, n, 0, flags);
    k_prop<<<pgrid, 256, 0, stream>>>(y0, y1, rowptr, col, wsrc, dinv, cvecs + 32, n, 0, flags);
    k_prop<<<pgrid, 256, 0, stream>>>(y1, d_out, rowptr, col, wsrc, dinv, cvecs + 48, n, 1, flags);
}

// Round 3
// 213.361 us; speedup vs baseline: 1.9007x; 1.1343x over previous
//
#include <hip/hip_runtime.h>
#include <hip/hip_bf16.h>
#include <stdint.h>

// ---------------- helpers ----------------
__device__ __forceinline__ float bf2f(unsigned short u) {
    unsigned int x = ((unsigned int)u) << 16;
    return __uint_as_float(x);
}
__device__ __forceinline__ unsigned short f2bf(float f) {
    unsigned int x = __float_as_uint(f);
    unsigned int lsb = (x >> 16) & 1u;
    x += 0x7fffu + lsb;           // round-to-nearest-even
    return (unsigned short)(x >> 16);
}
__device__ __forceinline__ float loadF(const void* p, int i, int isbf) {
    return isbf ? bf2f(((const unsigned short*)p)[i]) : ((const float*)p)[i];
}

#define NB 8   // dst-range buckets == XCD count

// ---------------- dtype detection (64-lane parallel) ----------------
// flags[0] = floats are bf16 (1) or f32 (0)
// flags[1] = edge_index is int64 (1) or int32 (0)
__global__ void k_detect(const void* x, const void* eidx, int* flags) {
    int l = threadIdx.x;   // 64 threads
    const unsigned short* u = (const unsigned short*)x;
    float a = fabsf(bf2f(u[2 * l]));
    bool ok = (a == 0.0f) || (a > 1e-30f && a < 1e4f);
    unsigned long long mbf = __ballot(ok);
    const int* ip = (const int*)eidx;
    unsigned long long mi64 = __ballot(ip[2 * l + 1] == 0);
    if (l == 0) {
        flags[0] = (mbf  == ~0ULL) ? 1 : 0;
        flags[1] = (mi64 == ~0ULL) ? 1 : 0;
    }
}

// ---------------- degree histogram, XCD-bucketed by dst range ----------------
__global__ void k_deg(const void* eidx, int E, int n, int* deg, const int* flags) {
    int i64 = flags[1];
    int bucket = blockIdx.x & (NB - 1);
    int chunk  = blockIdx.x >> 3;
    int nch    = gridDim.x >> 3;
    int lo = (int)((long long)bucket * n / NB);
    int hi = (int)((long long)(bucket + 1) * n / NB);
    int i0 = (int)((long long)chunk * E / nch);
    int i1 = (int)((long long)(chunk + 1) * E / nch);
    for (int i = i0 + threadIdx.x; i < i1; i += blockDim.x) {
        int d = i64 ? (int)((const long long*)eidx)[E + i] : ((const int*)eidx)[E + i];
        if (d >= lo && d < hi) atomicAdd(&deg[d], 1);
    }
}

// ---------------- exclusive scan of deg -> rowptr ----------------
__global__ void k_bsum(const int* deg, int n, int* bsum) {
    __shared__ int s[256];
    int b = blockIdx.x, t = threadIdx.x;
    int base = b * 1024;
    int v = 0;
    for (int k = t; k < 1024; k += 256) {
        int i = base + k;
        v += (i < n) ? deg[i] : 0;
    }
    s[t] = v; __syncthreads();
    for (int off = 128; off > 0; off >>= 1) {
        if (t < off) s[t] += s[t + off];
        __syncthreads();
    }
    if (t == 0) bsum[b] = s[0];
}
// parallel scan over block sums (nb <= 1024)
__global__ void k_scan_bsums(const int* bsum, int nb, int* boff, int* rowptr, int n) {
    __shared__ int s[1024];
    int t = threadIdx.x;   // 1024 threads
    int v = (t < nb) ? bsum[t] : 0;
    s[t] = v; __syncthreads();
    for (int off = 1; off < 1024; off <<= 1) {
        int add = (t >= off) ? s[t - off] : 0;
        __syncthreads();
        s[t] += add;
        __syncthreads();
    }
    if (t < nb) boff[t] = s[t] - v;          // exclusive
    if (t == nb - 1) rowptr[n] = s[t];       // == E
}
// fused: rowptr + cursor + dinv
__global__ void k_scan_write(const int* deg, int n, const int* boff, int* rowptr,
                             int* cursor, float* dinv) {
    __shared__ int s[1024];
    int b = blockIdx.x, t = threadIdx.x;
    int i = b * 1024 + t;
    int v = (i < n) ? deg[i] : 0;
    s[t] = v; __syncthreads();
    for (int off = 1; off < 1024; off <<= 1) {
        int add = (t >= off) ? s[t - off] : 0;
        __syncthreads();
        s[t] += add;
        __syncthreads();
    }
    if (i < n) {
        int r = boff[b] + s[t] - v;   // exclusive scan
        rowptr[i] = r;
        cursor[i] = r;
        dinv[i] = rsqrtf((float)(v + 1));   // +1 self loop
    }
}

// ---------------- CSR fill, XCD-bucketed by dst range ----------------
__global__ void k_fill(const void* eidx, int E, int n, int* cursor, int* col,
                       const int* flags) {
    int i64 = flags[1];
    int bucket = blockIdx.x & (NB - 1);
    int chunk  = blockIdx.x >> 3;
    int nch    = gridDim.x >> 3;
    int lo = (int)((long long)bucket * n / NB);
    int hi = (int)((long long)(bucket + 1) * n / NB);
    int i0 = (int)((long long)chunk * E / nch);
    int i1 = (int)((long long)(chunk + 1) * E / nch);
    for (int i = i0 + threadIdx.x; i < i1; i += blockDim.x) {
        int d = i64 ? (int)((const long long*)eidx)[E + i] : ((const int*)eidx)[E + i];
        if (d >= lo && d < hi) {
            int s = i64 ? (int)((const long long*)eidx)[i] : ((const int*)eidx)[i];
            int pos = atomicAdd(&cursor[d], 1);
            col[pos] = s;
        }
    }
}

// ---------------- consts: M = W1^3 W2 ; cvecs = {g3,g2,g1,b2} ----------------
#define TS 68
__global__ void k_consts(const void* W1, const void* b1, const void* W2, const void* b2,
                         float* M, float* cvecs, const int* flags) {
    __shared__ float A[64 * 64];       // row-major, stride 64
    __shared__ float T1[64 * TS];      // stride 68 (pad: bank-spread + 16B align)
    __shared__ float T2[64 * TS];
    __shared__ float B2[64 * 16];
    __shared__ float bv[64], bw1[64], bw2[64];
    int bf = flags[0];
    int t = threadIdx.x;   // 256 threads
    for (int i = t; i < 4096; i += 256) A[i] = loadF(W1, i, bf);
    for (int i = t; i < 1024; i += 256) B2[i] = loadF(W2, i, bf);
    if (t < 64) bv[t] = loadF(b1, t, bf);
    __syncthreads();

    const int i0 = (t >> 4) * 4;
    const int j0 = (t & 15) * 4;
    // ---- T1 = A @ A ----
    {
        float acc[4][4] = {};
#pragma unroll 8
        for (int k = 0; k < 64; ++k) {
            float a0 = A[(i0 + 0) * 64 + k];
            float a1 = A[(i0 + 1) * 64 + k];
            float a2 = A[(i0 + 2) * 64 + k];
            float a3 = A[(i0 + 3) * 64 + k];
            float4 bq = *(const float4*)&A[k * 64 + j0];
            acc[0][0] += a0 * bq.x; acc[0][1] += a0 * bq.y; acc[0][2] += a0 * bq.z; acc[0][3] += a0 * bq.w;
            acc[1][0] += a1 * bq.x; acc[1][1] += a1 * bq.y; acc[1][2] += a1 * bq.z; acc[1][3] += a1 * bq.w;
            acc[2][0] += a2 * bq.x; acc[2][1] += a2 * bq.y; acc[2][2] += a2 * bq.z; acc[2][3] += a2 * bq.w;
            acc[3][0] += a3 * bq.x; acc[3][1] += a3 * bq.y; acc[3][2] += a3 * bq.z; acc[3][3] += a3 * bq.w;
        }
#pragma unroll
        for (int ii = 0; ii < 4; ++ii)
            *(float4*)&T1[(i0 + ii) * TS + j0] = make_float4(acc[ii][0], acc[ii][1], acc[ii][2], acc[ii][3]);
    }
    if (t < 64) {
        float acc = 0.f;
#pragma unroll 8
        for (int i = 0; i < 64; ++i) acc += bv[i] * A[i * 64 + t];
        bw1[t] = acc;
    }
    __syncthreads();

    // ---- T2 = T1 @ A ----
    {
        float acc[4][4] = {};
#pragma unroll 8
        for (int k = 0; k < 64; ++k) {
            float a0 = T1[(i0 + 0) * TS + k];
            float a1 = T1[(i0 + 1) * TS + k];
            float a2 = T1[(i0 + 2) * TS + k];
            float a3 = T1[(i0 + 3) * TS + k];
            float4 bq = *(const float4*)&A[k * 64 + j0];
            acc[0][0] += a0 * bq.x; acc[0][1] += a0 * bq.y; acc[0][2] += a0 * bq.z; acc[0][3] += a0 * bq.w;
            acc[1][0] += a1 * bq.x; acc[1][1] += a1 * bq.y; acc[1][2] += a1 * bq.z; acc[1][3] += a1 * bq.w;
            acc[2][0] += a2 * bq.x; acc[2][1] += a2 * bq.y; acc[2][2] += a2 * bq.z; acc[2][3] += a2 * bq.w;
            acc[3][0] += a3 * bq.x; acc[3][1] += a3 * bq.y; acc[3][2] += a3 * bq.z; acc[3][3] += a3 * bq.w;
        }
#pragma unroll
        for (int ii = 0; ii < 4; ++ii)
            *(float4*)&T2[(i0 + ii) * TS + j0] = make_float4(acc[ii][0], acc[ii][1], acc[ii][2], acc[ii][3]);
    }
    if (t < 64) {
        float acc = 0.f;
#pragma unroll 8
        for (int i = 0; i < 64; ++i) acc += bw1[i] * A[i * 64 + t];
        bw2[t] = acc;
    }
    __syncthreads();

    // ---- M = T2 @ B2 (64x16) ----
    {
        int i = t >> 2, j0m = (t & 3) * 4;
        float4 acc = {0.f, 0.f, 0.f, 0.f};
#pragma unroll 8
        for (int k = 0; k < 64; ++k) {
            float a = T2[i * TS + k];
            float4 bq = *(const float4*)&B2[k * 16 + j0m];
            acc.x += a * bq.x; acc.y += a * bq.y; acc.z += a * bq.z; acc.w += a * bq.w;
        }
        *(float4*)&M[i * 16 + j0m] = acc;
    }
    // cvecs: [0:16)=g3=b1W1^2W2, [16:32)=g2=b1W1W2, [32:48)=g1=b1W2, [48:64)=b2
    if (t < 16) {
        float a3 = 0.f, a2 = 0.f, a1 = 0.f;
#pragma unroll 8
        for (int i = 0; i < 64; ++i) {
            float w = B2[i * 16 + t];
            a3 += bw2[i] * w;
            a2 += bw1[i] * w;
            a1 += bv[i] * w;
        }
        cvecs[t] = a3;
        cvecs[16 + t] = a2;
        cvecs[32 + t] = a1;
        cvecs[48 + t] = loadF(b2, t, bf);
    }
}

// ---------------- z0 = dinv * (x @ M)  (N x 64 @ 64 x 16) ----------------
__global__ void k_xm(const void* x, const float* M, const float* dinv, float* z0,
                     int n, const int* flags) {
    __shared__ float Ms[64 * 16];
    __shared__ float xs[16 * 64];
    int bf = flags[0];
    int t = threadIdx.x;   // 256
    ((float4*)Ms)[t] = ((const float4*)M)[t];
    int base = blockIdx.x * 16;
    if (!bf) {
        int row = base + (t >> 4);
        float4 v = make_float4(0.f, 0.f, 0.f, 0.f);
        if (row < n) v = ((const float4*)x)[base * 16 + t];
        ((float4*)xs)[t] = v;
    } else {
        for (int k = t; k < 1024; k += 256) {
            int r = k >> 6, cc = k & 63;
            int row = base + r;
            xs[k] = (row < n) ? bf2f(((const unsigned short*)x)[row * 64 + cc]) : 0.f;
        }
    }
    __syncthreads();
    int r = t >> 4, c = t & 15;
    int row = base + r;
    if (row < n) {
        float acc = 0.f;
#pragma unroll
        for (int k = 0; k < 64; ++k) acc += xs[r * 64 + k] * Ms[k * 16 + c];
        z0[row * 16 + c] = dinv[row] * acc;   // z-space
    }
}

// ---------------- propagation in z-space (float4 per lane, 4 lanes per node) ----
// sum = z[v] + sum_{s in N(v)} z[s]
// non-final: zout = dinv^2*sum + dinv*cvec ; final: yout = dinv*sum + cvec
__global__ void k_prop(const float* zin, void* yout, const int* rowptr, const int* col,
                       const float* dinv, const float* cvec,
                       int n, int is_final, const int* flags) {
    int tid = blockIdx.x * blockDim.x + threadIdx.x;
    int v = tid >> 2, q = tid & 3;
    if (v >= n) return;
    int beg = rowptr[v], end = rowptr[v + 1];
    float4 acc = *(const float4*)&zin[v * 16 + q * 4];   // self-loop term
    for (int j = beg; j < end; ++j) {
        int ci = col[j];
        float4 zv = *(const float4*)&zin[ci * 16 + q * 4];
        acc.x += zv.x; acc.y += zv.y; acc.z += zv.z; acc.w += zv.w;
    }
    float dv = dinv[v];
    float a = is_final ? dv : dv * dv;
    float b = is_final ? 1.0f : dv;
    float4 cv = *(const float4*)&cvec[q * 4];
    float4 val;
    val.x = a * acc.x + b * cv.x;
    val.y = a * acc.y + b * cv.y;
    val.z = a * acc.z + b * cv.z;
    val.w = a * acc.w + b * cv.w;
    int o = v * 16 + q * 4;
    if (is_final && flags[0]) {
        ushort4 ov;
        ov.x = f2bf(val.x); ov.y = f2bf(val.y); ov.z = f2bf(val.z); ov.w = f2bf(val.w);
        *(ushort4*)&((unsigned short*)yout)[o] = ov;
    } else {
        *(float4*)&((float*)yout)[o] = val;
    }
}

// ---------------- launch ----------------
extern "C" void kernel_launch(void* const* d_in, const int* in_sizes, int n_in,
                              void* d_out, int out_size, void* d_ws, size_t ws_size,
                              hipStream_t stream) {
    const void* x  = d_in[0];
    const void* W1 = d_in[1];
    const void* b1 = d_in[2];
    const void* W2 = d_in[3];
    const void* b2 = d_in[4];
    const void* ei = d_in[5];

    const int n = in_sizes[0] / 64;       // 100000
    const int E = in_sizes[5] / 2;        // 1000000
    const int nb = (n + 1023) / 1024;

    char* base = (char*)d_ws;
    size_t off = 0;
    auto carve = [&](size_t bytes) -> void* {
        void* r = base + off;
        off = (off + bytes + 255) & ~(size_t)255;
        return r;
    };
    int*   flags  = (int*)carve(8);
    int*   deg    = (int*)carve((size_t)n * 4);
    float* dinv   = (float*)carve((size_t)n * 4);
    int*   rowptr = (int*)carve((size_t)(n + 1) * 4);
    int*   cursor = (int*)carve((size_t)n * 4);
    int*   bsum   = (int*)carve((size_t)nb * 4);
    int*   boff   = (int*)carve((size_t)nb * 4);
    int*   col    = (int*)carve((size_t)E * 4);
    float* Mm     = (float*)carve(1024 * 4);
    float* cvecs  = (float*)carve(64 * 4);
    float* z0     = (float*)carve((size_t)n * 16 * 4);
    float* z1     = (float*)carve((size_t)n * 16 * 4);
    (void)ws_size; (void)n_in; (void)out_size;

    hipMemsetAsync(deg, 0, (size_t)n * 4, stream);
    k_detect<<<1, 64, 0, stream>>>(x, ei, flags);
    k_deg<<<2048, 256, 0, stream>>>(ei, E, n, deg, flags);        // 8 buckets x 256 chunks
    k_bsum<<<nb, 256, 0, stream>>>(deg, n, bsum);
    k_scan_bsums<<<1, 1024, 0, stream>>>(bsum, nb, boff, rowptr, n);
    k_scan_write<<<nb, 1024, 0, stream>>>(deg, n, boff, rowptr, cursor, dinv);
    k_fill<<<2048, 256, 0, stream>>>(ei, E, n, cursor, col, flags);
    k_consts<<<1, 256, 0, stream>>>(W1, b1, W2, b2, Mm, cvecs, flags);
    k_xm<<<(n + 15) / 16, 256, 0, stream>>>(x, Mm, dinv, z0, n, flags);

    const int pgrid = (n * 4 + 255) / 256;
    // z1 = P z0 + .. ; z0 = P z1 + .. ; z1 = P z0 + .. ; out = final(P z1) + b2
    k_prop<<<pgrid, 256, 0, stream>>>(z0, z1, rowptr, col, dinv, cvecs + 0,  n, 0, flags);
    k_prop<<<pgrid, 256, 0, stream>>>(z1, z0, rowptr, col, dinv, cvecs + 16, n, 0, flags);
    k_prop<<<pgrid, 256, 0, stream>>>(z0, z1, rowptr, col, dinv, cvecs + 32, n, 0, flags);
    k_prop<<<pgrid, 256, 0, stream>>>(z1, d_out, rowptr, col, dinv, cvecs + 48, n, 1, flags);
}